// Round 5
// baseline (30.057 us; speedup 1.0000x reference)
//
#include <hip/hip_runtime.h>
#include <hip/hip_bf16.h>

#define NB   32      // batch N
#define NRR  48      // rows NR
#define TT   2048    // temporal length T
#define DD   256     // d_model
#define QQ   32      // query points
#define ROWS (NB * NRR)   // 1536 total rows
#define NXCD 8

typedef float f32x4 __attribute__((ext_vector_type(4)));

// One block per (n, r) row; 256 threads = 4 waves; wave wv owns q = 8*wv..8*wv+7.
// Gather indices are wave-uniform -> readfirstlane to SGPR so loads become
// scalar-base + lane-offset (d4). Query points processed in PAIRS: 16 clamped,
// coefficient-masked loads issued as one burst (MLP=16), consumed in order.
__global__ __launch_bounds__(256) void pd_kernel(
    const float* __restrict__ pro,     // (N, NR, D)
    const float* __restrict__ feat,    // (N, T, D)
    const float* __restrict__ sp,      // (N, NR, Q)
    const float* __restrict__ w_bo, const float* __restrict__ b_bo,
    const float* __restrict__ w_co, const float* __restrict__ b_co,
    const float* __restrict__ w_bw, const float* __restrict__ b_bw,
    const float* __restrict__ w_cw, const float* __restrict__ b_cw,
    float* __restrict__ out)           // (Q, ROWS, D)
{
    // XCD-aware swizzle: hardware block b -> XCD b%8; XCD k gets contiguous
    // rows [k*192,(k+1)*192) so resident blocks share few feature slices in L2.
    const int bid = blockIdx.x;
    const int row = (bid & (NXCD - 1)) * (ROWS / NXCD) + (bid >> 3);
    const int n    = row / NRR;
    const int lane = threadIdx.x & 63;
    const int wv   = threadIdx.x >> 6;      // wave 0..3
    const int d4   = lane << 2;             // channel base (float4 per lane)

    // ---- 16 dot products of pro[row,:] with the 4x4 weight rows ----
    const f32x4 p = *reinterpret_cast<const f32x4*>(pro + (size_t)row * DD + d4);

    float acc[16];
#pragma unroll
    for (int s = 0; s < 4; ++s) {
        f32x4 w;
        w = *reinterpret_cast<const f32x4*>(w_bo + s * DD + d4);
        acc[s]      = p.x * w.x + p.y * w.y + p.z * w.z + p.w * w.w;
        w = *reinterpret_cast<const f32x4*>(w_co + s * DD + d4);
        acc[4 + s]  = p.x * w.x + p.y * w.y + p.z * w.z + p.w * w.w;
        w = *reinterpret_cast<const f32x4*>(w_bw + s * DD + d4);
        acc[8 + s]  = p.x * w.x + p.y * w.y + p.z * w.z + p.w * w.w;
        w = *reinterpret_cast<const f32x4*>(w_cw + s * DD + d4);
        acc[12 + s] = p.x * w.x + p.y * w.y + p.z * w.z + p.w * w.w;
    }
    // 64-lane butterfly reduce; every lane ends with the full dot values.
#pragma unroll
    for (int st = 1; st < 64; st <<= 1) {
#pragma unroll
        for (int k = 0; k < 16; ++k)
            acc[k] += __shfl_xor(acc[k], st, 64);
    }

    float bo[4], co[4], bw[4], cw[4];
#pragma unroll
    for (int s = 0; s < 4; ++s) {
        bo[s] = acc[s]      + b_bo[s];
        co[s] = acc[4 + s]  + b_co[s];
        bw[s] = acc[8 + s]  + b_bw[s];
        cw[s] = acc[12 + s] + b_cw[s];
    }
    // softmax over s (max-subtracted), then fold the 0.5 row weight in.
    {
        float mb = fmaxf(fmaxf(bw[0], bw[1]), fmaxf(bw[2], bw[3]));
        float mc = fmaxf(fmaxf(cw[0], cw[1]), fmaxf(cw[2], cw[3]));
        float sb = 0.f, sc = 0.f;
#pragma unroll
        for (int s = 0; s < 4; ++s) { bw[s] = expf(bw[s] - mb); sb += bw[s]; }
#pragma unroll
        for (int s = 0; s < 4; ++s) { cw[s] = expf(cw[s] - mc); sc += cw[s]; }
        const float rb = 0.5f / sb, rc = 0.5f / sc;   // 0.5 = y=-1 row weight
#pragma unroll
        for (int s = 0; s < 4; ++s) { bw[s] *= rb; cw[s] *= rc; }
    }

    // ---- gather + mix: q-pairs, 16-load bursts with scalar base addressing ----
    const float* fnrow = feat + (size_t)n * (TT * DD);   // wave-uniform base
    const float* spr   = sp + (size_t)row * QQ;
    const float  inv_w = 1.0f / 2048.0f;

#pragma unroll
    for (int j2 = 0; j2 < 4; ++j2) {
        int   idx[16];
        float cc[16];
#pragma unroll
        for (int h = 0; h < 2; ++h) {
            const int   q     = (wv << 3) + (j2 << 1) + h;
            const bool  isB   = (q < 4);             // wave-uniform
            const float point = spr[q];
#pragma unroll
            for (int s = 0; s < 4; ++s) {
                const float off = (isB ? bo[s] : co[s]) * inv_w;
                const float loc = fminf(fmaxf(point + off, 0.f), 1.f);
                const float px  = loc * (float)TT - 0.5f;
                const float x0f = floorf(px);
                const float w1  = px - x0f;          // right-neighbor weight
                const int   x0  = (int)x0f;          // in [-1, 2047]
                const int   x0c = x0 < 0 ? 0 : x0;
                const int   x1c = x0 + 1 > TT - 1 ? TT - 1 : x0 + 1;
                const float wgt = isB ? bw[s] : cw[s];
                const int   k   = (h << 3) + (s << 1);
                cc[k]     = (x0 >= 0)     ? wgt * (1.f - w1) : 0.f;
                cc[k + 1] = (x0 + 1 < TT) ? wgt * w1         : 0.f;
                // indices are wave-uniform: pin them to SGPRs so the loads
                // become scalar-base + lane-offset (saddr form).
                idx[k]     = __builtin_amdgcn_readfirstlane(x0c) * DD;
                idx[k + 1] = __builtin_amdgcn_readfirstlane(x1c) * DD;
            }
        }

        f32x4 g[16];
#pragma unroll
        for (int k = 0; k < 16; ++k)
            g[k] = *reinterpret_cast<const f32x4*>(fnrow + idx[k] + d4);

        f32x4 o0 = {0.f, 0.f, 0.f, 0.f};
        f32x4 o1 = {0.f, 0.f, 0.f, 0.f};
#pragma unroll
        for (int k = 0; k < 8; ++k)  o0 += cc[k] * g[k];
#pragma unroll
        for (int k = 8; k < 16; ++k) o1 += cc[k] * g[k];

        const int q0 = (wv << 3) + (j2 << 1);
        __builtin_nontemporal_store(o0,
            reinterpret_cast<f32x4*>(out + ((size_t)q0 * ROWS + row) * DD + d4));
        __builtin_nontemporal_store(o1,
            reinterpret_cast<f32x4*>(out + ((size_t)(q0 + 1) * ROWS + row) * DD + d4));
    }
}

extern "C" void kernel_launch(void* const* d_in, const int* in_sizes, int n_in,
                              void* d_out, int out_size, void* d_ws, size_t ws_size,
                              hipStream_t stream) {
    const float* pro  = (const float*)d_in[0];
    const float* feat = (const float*)d_in[1];
    const float* sp   = (const float*)d_in[2];
    const float* w_bo = (const float*)d_in[3];
    const float* b_bo = (const float*)d_in[4];
    const float* w_co = (const float*)d_in[5];
    const float* b_co = (const float*)d_in[6];
    const float* w_bw = (const float*)d_in[7];
    const float* b_bw = (const float*)d_in[8];
    const float* w_cw = (const float*)d_in[9];
    const float* b_cw = (const float*)d_in[10];
    float* out = (float*)d_out;

    pd_kernel<<<ROWS, 256, 0, stream>>>(
        pro, feat, sp, w_bo, b_bo, w_co, b_co, w_bw, b_bw, w_cw, b_cw, out);
}

// Round 6
// 28.219 us; speedup vs baseline: 1.0652x; 1.0652x over previous
//
#include <hip/hip_runtime.h>
#include <hip/hip_bf16.h>

#define NB   32      // batch N
#define NRR  48      // rows NR
#define TT   2048    // temporal length T
#define DD   256     // d_model
#define QQ   32      // query points
#define ROWS (NB * NRR)   // 1536 total rows
#define NXCD 8

typedef float f32x4 __attribute__((ext_vector_type(4)));

// One block per (n, r) row; 256 threads = 4 waves; wave wv owns q = 8*wv..8*wv+7.
// Gather indices are wave-uniform -> readfirstlane to SGPR (saddr-form loads).
// Query points processed in PAIRS: 16 clamped, coefficient-masked loads issued
// as one burst. A sched_barrier(0) between the burst and its FMAs FORCES the
// compiler to keep all 16 loads in flight (MLP=16) instead of sinking each
// load next to its use (R5 showed VGPR=32 => MLP~4, latency-bound).
__global__ __launch_bounds__(256) void pd_kernel(
    const float* __restrict__ pro,     // (N, NR, D)
    const float* __restrict__ feat,    // (N, T, D)
    const float* __restrict__ sp,      // (N, NR, Q)
    const float* __restrict__ w_bo, const float* __restrict__ b_bo,
    const float* __restrict__ w_co, const float* __restrict__ b_co,
    const float* __restrict__ w_bw, const float* __restrict__ b_bw,
    const float* __restrict__ w_cw, const float* __restrict__ b_cw,
    float* __restrict__ out)           // (Q, ROWS, D)
{
    // XCD-aware swizzle: hardware block b -> XCD b%8; XCD k gets contiguous
    // rows [k*192,(k+1)*192) so resident blocks share few feature slices in L2.
    const int bid = blockIdx.x;
    const int row = (bid & (NXCD - 1)) * (ROWS / NXCD) + (bid >> 3);
    const int n    = row / NRR;
    const int lane = threadIdx.x & 63;
    const int wv   = threadIdx.x >> 6;      // wave 0..3
    const int d4   = lane << 2;             // channel base (float4 per lane)

    // ---- 16 dot products of pro[row,:] with the 4x4 weight rows ----
    const f32x4 p = *reinterpret_cast<const f32x4*>(pro + (size_t)row * DD + d4);

    float acc[16];
#pragma unroll
    for (int s = 0; s < 4; ++s) {
        f32x4 w;
        w = *reinterpret_cast<const f32x4*>(w_bo + s * DD + d4);
        acc[s]      = p.x * w.x + p.y * w.y + p.z * w.z + p.w * w.w;
        w = *reinterpret_cast<const f32x4*>(w_co + s * DD + d4);
        acc[4 + s]  = p.x * w.x + p.y * w.y + p.z * w.z + p.w * w.w;
        w = *reinterpret_cast<const f32x4*>(w_bw + s * DD + d4);
        acc[8 + s]  = p.x * w.x + p.y * w.y + p.z * w.z + p.w * w.w;
        w = *reinterpret_cast<const f32x4*>(w_cw + s * DD + d4);
        acc[12 + s] = p.x * w.x + p.y * w.y + p.z * w.z + p.w * w.w;
    }
    // 64-lane butterfly reduce; every lane ends with the full dot values.
#pragma unroll
    for (int st = 1; st < 64; st <<= 1) {
#pragma unroll
        for (int k = 0; k < 16; ++k)
            acc[k] += __shfl_xor(acc[k], st, 64);
    }

    float bo[4], co[4], bw[4], cw[4];
#pragma unroll
    for (int s = 0; s < 4; ++s) {
        bo[s] = acc[s]      + b_bo[s];
        co[s] = acc[4 + s]  + b_co[s];
        bw[s] = acc[8 + s]  + b_bw[s];
        cw[s] = acc[12 + s] + b_cw[s];
    }
    // softmax over s (max-subtracted), then fold the 0.5 row weight in.
    {
        float mb = fmaxf(fmaxf(bw[0], bw[1]), fmaxf(bw[2], bw[3]));
        float mc = fmaxf(fmaxf(cw[0], cw[1]), fmaxf(cw[2], cw[3]));
        float sb = 0.f, sc = 0.f;
#pragma unroll
        for (int s = 0; s < 4; ++s) { bw[s] = expf(bw[s] - mb); sb += bw[s]; }
#pragma unroll
        for (int s = 0; s < 4; ++s) { cw[s] = expf(cw[s] - mc); sc += cw[s]; }
        const float rb = 0.5f / sb, rc = 0.5f / sc;   // 0.5 = y=-1 row weight
#pragma unroll
        for (int s = 0; s < 4; ++s) { bw[s] *= rb; cw[s] *= rc; }
    }

    // ---- gather + mix: q-pairs, forced 16-load bursts ----
    const float* fnrow = feat + (size_t)n * (TT * DD);   // wave-uniform base
    const float* spr   = sp + (size_t)row * QQ;
    const float  inv_w = 1.0f / 2048.0f;

#pragma unroll
    for (int j2 = 0; j2 < 4; ++j2) {
        int   idx[16];
        float cc[16];
#pragma unroll
        for (int h = 0; h < 2; ++h) {
            const int   q     = (wv << 3) + (j2 << 1) + h;
            const bool  isB   = (q < 4);             // wave-uniform
            const float point = spr[q];
#pragma unroll
            for (int s = 0; s < 4; ++s) {
                const float off = (isB ? bo[s] : co[s]) * inv_w;
                const float loc = fminf(fmaxf(point + off, 0.f), 1.f);
                const float px  = loc * (float)TT - 0.5f;
                const float x0f = floorf(px);
                const float w1  = px - x0f;          // right-neighbor weight
                const int   x0  = (int)x0f;          // in [-1, 2047]
                const int   x0c = x0 < 0 ? 0 : x0;
                const int   x1c = x0 + 1 > TT - 1 ? TT - 1 : x0 + 1;
                const float wgt = isB ? bw[s] : cw[s];
                const int   k   = (h << 3) + (s << 1);
                cc[k]     = (x0 >= 0)     ? wgt * (1.f - w1) : 0.f;
                cc[k + 1] = (x0 + 1 < TT) ? wgt * w1         : 0.f;
                idx[k]     = __builtin_amdgcn_readfirstlane(x0c) * DD;
                idx[k + 1] = __builtin_amdgcn_readfirstlane(x1c) * DD;
            }
        }

        f32x4 g[16];
#pragma unroll
        for (int k = 0; k < 16; ++k)
            g[k] = *reinterpret_cast<const f32x4*>(fnrow + idx[k] + d4);

        // Pin the schedule: all 16 loads issued before any consumer ->
        // 16 outstanding vmem ops per wave instead of ~4.
        __builtin_amdgcn_sched_barrier(0);

        f32x4 o0 = {0.f, 0.f, 0.f, 0.f};
        f32x4 o1 = {0.f, 0.f, 0.f, 0.f};
#pragma unroll
        for (int k = 0; k < 8; ++k)  o0 += cc[k] * g[k];
#pragma unroll
        for (int k = 8; k < 16; ++k) o1 += cc[k] * g[k];

        const int q0 = (wv << 3) + (j2 << 1);
        __builtin_nontemporal_store(o0,
            reinterpret_cast<f32x4*>(out + ((size_t)q0 * ROWS + row) * DD + d4));
        __builtin_nontemporal_store(o1,
            reinterpret_cast<f32x4*>(out + ((size_t)(q0 + 1) * ROWS + row) * DD + d4));
    }
}

extern "C" void kernel_launch(void* const* d_in, const int* in_sizes, int n_in,
                              void* d_out, int out_size, void* d_ws, size_t ws_size,
                              hipStream_t stream) {
    const float* pro  = (const float*)d_in[0];
    const float* feat = (const float*)d_in[1];
    const float* sp   = (const float*)d_in[2];
    const float* w_bo = (const float*)d_in[3];
    const float* b_bo = (const float*)d_in[4];
    const float* w_co = (const float*)d_in[5];
    const float* b_co = (const float*)d_in[6];
    const float* w_bw = (const float*)d_in[7];
    const float* b_bw = (const float*)d_in[8];
    const float* w_cw = (const float*)d_in[9];
    const float* b_cw = (const float*)d_in[10];
    float* out = (float*)d_out;

    pd_kernel<<<ROWS, 256, 0, stream>>>(
        pro, feat, sp, w_bo, b_bo, w_co, b_co, w_bw, b_bw, w_cw, b_cw, out);
}